// Round 1
// baseline (29060.635 us; speedup 1.0000x reference)
//
#include <hip/hip_runtime.h>
#include <math.h>

#define Bsz 64
#define Tlen 1024
#define Idim 256
#define Hdim 512
#define Odim 256

// ---------------------------------------------------------------------------
// Kernel A: xproj[b][t][h] = dot(x[b, t0+t, :], Wi[h, :]) + bi[h] + bh[h]
// GEMM M=(Bsz*CT) x N=512, K=256. Tile 128x128, 256 threads, KT=16.
// xp layout: [b][t_local][h], row index m = b*CT + t_local.
// ---------------------------------------------------------------------------
__global__ __launch_bounds__(256) void xproj_kernel(
        const float* __restrict__ x, const float* __restrict__ Wi,
        const float* __restrict__ bi, const float* __restrict__ bh,
        float* __restrict__ xp, int t0, int CT) {
    __shared__ float As[16][132];   // [k][m], padded row 132 floats
    __shared__ float Bs[16][132];   // [k][n]
    const int tid = threadIdx.x;
    const int bm = blockIdx.x, bn = blockIdx.y;
    const int tx = tid & 15, ty = tid >> 4;

    // Staging assignments: 512 float4 per tile for A (and for B); 2 each.
    const int f0 = tid, f1 = tid + 256;
    const int ar0 = f0 >> 2, ak0 = (f0 & 3) * 4;
    const int ar1 = f1 >> 2, ak1 = (f1 & 3) * 4;
    const int m0g = bm * 128 + ar0;
    const int m1g = bm * 128 + ar1;
    const int b0 = m0g / CT, tt0 = m0g - b0 * CT;
    const int b1 = m1g / CT, tt1 = m1g - b1 * CT;
    const float* xrow0 = x + ((size_t)b0 * Tlen + t0 + tt0) * Idim;
    const float* xrow1 = x + ((size_t)b1 * Tlen + t0 + tt1) * Idim;
    const float* wrow0 = Wi + (size_t)(bn * 128 + ar0) * Idim;
    const float* wrow1 = Wi + (size_t)(bn * 128 + ar1) * Idim;

    float acc[8][8];
#pragma unroll
    for (int i = 0; i < 8; ++i)
#pragma unroll
        for (int j = 0; j < 8; ++j) acc[i][j] = 0.0f;

    for (int kk = 0; kk < Idim; kk += 16) {
        float4 av0 = *(const float4*)(xrow0 + kk + ak0);
        float4 av1 = *(const float4*)(xrow1 + kk + ak1);
        float4 bv0 = *(const float4*)(wrow0 + kk + ak0);
        float4 bv1 = *(const float4*)(wrow1 + kk + ak1);
        __syncthreads();
        As[ak0 + 0][ar0] = av0.x; As[ak0 + 1][ar0] = av0.y;
        As[ak0 + 2][ar0] = av0.z; As[ak0 + 3][ar0] = av0.w;
        As[ak1 + 0][ar1] = av1.x; As[ak1 + 1][ar1] = av1.y;
        As[ak1 + 2][ar1] = av1.z; As[ak1 + 3][ar1] = av1.w;
        Bs[ak0 + 0][ar0] = bv0.x; Bs[ak0 + 1][ar0] = bv0.y;
        Bs[ak0 + 2][ar0] = bv0.z; Bs[ak0 + 3][ar0] = bv0.w;
        Bs[ak1 + 0][ar1] = bv1.x; Bs[ak1 + 1][ar1] = bv1.y;
        Bs[ak1 + 2][ar1] = bv1.z; Bs[ak1 + 3][ar1] = bv1.w;
        __syncthreads();
#pragma unroll
        for (int k = 0; k < 16; ++k) {
            float4 a0 = *(const float4*)&As[k][tx * 4];
            float4 a1 = *(const float4*)&As[k][64 + tx * 4];
            float4 bq0 = *(const float4*)&Bs[k][ty * 4];
            float4 bq1 = *(const float4*)&Bs[k][64 + ty * 4];
            float a[8] = {a0.x, a0.y, a0.z, a0.w, a1.x, a1.y, a1.z, a1.w};
            float bb[8] = {bq0.x, bq0.y, bq0.z, bq0.w, bq1.x, bq1.y, bq1.z, bq1.w};
#pragma unroll
            for (int i = 0; i < 8; ++i)
#pragma unroll
                for (int j = 0; j < 8; ++j) acc[i][j] += a[i] * bb[j];
        }
    }

    // Epilogue: add bias (bi+bh), write float4 pairs per row.
    const int n0 = bn * 128;
    float biasv[8];
#pragma unroll
    for (int j = 0; j < 8; ++j) {
        int c = (j < 4) ? (ty * 4 + j) : (64 + ty * 4 + (j - 4));
        biasv[j] = bi[n0 + c] + bh[n0 + c];
    }
#pragma unroll
    for (int i = 0; i < 8; ++i) {
        int r = (i < 4) ? (tx * 4 + i) : (64 + tx * 4 + (i - 4));
        size_t mrow = (size_t)(bm * 128 + r);
        float4 o0 = {acc[i][0] + biasv[0], acc[i][1] + biasv[1],
                     acc[i][2] + biasv[2], acc[i][3] + biasv[3]};
        float4 o1 = {acc[i][4] + biasv[4], acc[i][5] + biasv[5],
                     acc[i][6] + biasv[6], acc[i][7] + biasv[7]};
        *(float4*)(xp + mrow * Hdim + n0 + ty * 4) = o0;
        *(float4*)(xp + mrow * Hdim + n0 + 64 + ty * 4) = o1;
    }
}

// ---------------------------------------------------------------------------
// Kernel B: sequential scan. One workgroup per batch row (no grid sync
// needed!). 512 threads; thread j owns output row j of h_next.
// h kept in LDS double-buffered (one barrier per step). Wh streamed from L2
// (1 MB/step/CU -> the expected bottleneck). 4 independent FMA chains.
// ---------------------------------------------------------------------------
__global__ __launch_bounds__(512) void scan_kernel(
        const float* __restrict__ xp, const float* __restrict__ Wh,
        float* __restrict__ hbuf, int t0, int CT) {
    __shared__ float hs[2][Hdim];
    const int b = blockIdx.x;
    const int j = threadIdx.x;
    hs[0][j] = (t0 == 0) ? 0.0f : hbuf[b * Hdim + j];
    __syncthreads();

    const float4* wrow = (const float4*)(Wh + (size_t)j * Hdim);
    const float* xpb = xp + (size_t)b * CT * Hdim;
    int p = 0;
    for (int t = 0; t < CT; ++t) {
        const float4* h4 = (const float4*)hs[p];
        float4 a4 = {0.0f, 0.0f, 0.0f, 0.0f};
#pragma unroll 4
        for (int i = 0; i < Hdim / 4; ++i) {
            float4 w = wrow[i];
            float4 hv = h4[i];
            a4.x += w.x * hv.x;
            a4.y += w.y * hv.y;
            a4.z += w.z * hv.z;
            a4.w += w.w * hv.w;
        }
        float acc = xpb[(size_t)t * Hdim + j] + ((a4.x + a4.y) + (a4.z + a4.w));
        hs[1 - p][j] = tanhf(acc);
        __syncthreads();
        p ^= 1;
    }
    hbuf[b * Hdim + j] = hs[p][j];
}

// ---------------------------------------------------------------------------
// Kernel C: out[b][o] = dot(h_final[b,:], Wo[o,:]) + bo[o]
// ---------------------------------------------------------------------------
__global__ __launch_bounds__(256) void out_kernel(
        const float* __restrict__ hbuf, const float* __restrict__ Wo,
        const float* __restrict__ bo, float* __restrict__ out) {
    __shared__ float hs[Hdim];
    const int b = blockIdx.x, o = threadIdx.x;
    hs[o] = hbuf[b * Hdim + o];
    hs[o + 256] = hbuf[b * Hdim + o + 256];
    __syncthreads();
    const float4* wrow = (const float4*)(Wo + (size_t)o * Hdim);
    const float4* h4 = (const float4*)hs;
    float4 a4 = {0.0f, 0.0f, 0.0f, 0.0f};
#pragma unroll 4
    for (int i = 0; i < Hdim / 4; ++i) {
        float4 w = wrow[i];
        float4 hv = h4[i];
        a4.x += w.x * hv.x;
        a4.y += w.y * hv.y;
        a4.z += w.z * hv.z;
        a4.w += w.w * hv.w;
    }
    out[b * Odim + o] = bo[o] + ((a4.x + a4.y) + (a4.z + a4.w));
}

// ---------------------------------------------------------------------------
extern "C" void kernel_launch(void* const* d_in, const int* in_sizes, int n_in,
                              void* d_out, int out_size, void* d_ws, size_t ws_size,
                              hipStream_t stream) {
    const float* x  = (const float*)d_in[0];
    const float* Wi = (const float*)d_in[1];
    const float* bi = (const float*)d_in[2];
    const float* Wh = (const float*)d_in[3];
    const float* bh = (const float*)d_in[4];
    const float* Wo = (const float*)d_in[5];
    const float* bo = (const float*)d_in[6];
    float* out = (float*)d_out;

    // Chunk the timeline so the xproj staging buffer fits in ws.
    const size_t hbytes = (size_t)Bsz * Hdim * sizeof(float);
    int CT = Tlen;
    while (CT > 2 && (size_t)Bsz * CT * Hdim * sizeof(float) + hbytes > ws_size)
        CT >>= 1;

    float* xp   = (float*)d_ws;
    float* hbuf = (float*)((char*)d_ws + (size_t)Bsz * CT * Hdim * sizeof(float));

    for (int t0 = 0; t0 < Tlen; t0 += CT) {
        xproj_kernel<<<dim3((Bsz * CT) / 128, Hdim / 128), 256, 0, stream>>>(
            x, Wi, bi, bh, xp, t0, CT);
        scan_kernel<<<dim3(Bsz), 512, 0, stream>>>(xp, Wh, hbuf, t0, CT);
    }
    out_kernel<<<dim3(Bsz), 256, 0, stream>>>(hbuf, Wo, bo, out);
}

// Round 2
// 5558.023 us; speedup vs baseline: 5.2286x; 5.2286x over previous
//
#include <hip/hip_runtime.h>
#include <math.h>

#define Bsz 64
#define Tlen 1024
#define Idim 256
#define Hdim 512
#define Odim 256

#define PB  4              // batches per sync-group
#define NSL 8              // column slices = WGs per group
#define NG  (Bsz / PB)     // 16 groups -> 128 WGs total

// ---------------------------------------------------------------------------
// Kernel A: xproj[b][t][h] = dot(x[b, t0+t, :], Wi[h, :]) + bi[h] + bh[h]
// GEMM M=(Bsz*CT) x N=512, K=256. Tile 128x128, 256 threads.
// xp layout: [b][t_local][h], row index m = b*CT + t_local.
// ---------------------------------------------------------------------------
__global__ __launch_bounds__(256) void xproj_kernel(
        const float* __restrict__ x, const float* __restrict__ Wi,
        const float* __restrict__ bi, const float* __restrict__ bh,
        float* __restrict__ xp, int t0, int CT) {
    __shared__ float As[16][132];   // [k][m]
    __shared__ float Bs[16][132];   // [k][n]
    const int tid = threadIdx.x;
    const int bm = blockIdx.x, bn = blockIdx.y;
    const int tx = tid & 15, ty = tid >> 4;

    const int f0 = tid, f1 = tid + 256;
    const int ar0 = f0 >> 2, ak0 = (f0 & 3) * 4;
    const int ar1 = f1 >> 2, ak1 = (f1 & 3) * 4;
    const int m0g = bm * 128 + ar0;
    const int m1g = bm * 128 + ar1;
    const int b0 = m0g / CT, tt0 = m0g - b0 * CT;
    const int b1 = m1g / CT, tt1 = m1g - b1 * CT;
    const float* xrow0 = x + ((size_t)b0 * Tlen + t0 + tt0) * Idim;
    const float* xrow1 = x + ((size_t)b1 * Tlen + t0 + tt1) * Idim;
    const float* wrow0 = Wi + (size_t)(bn * 128 + ar0) * Idim;
    const float* wrow1 = Wi + (size_t)(bn * 128 + ar1) * Idim;

    float acc[8][8];
#pragma unroll
    for (int i = 0; i < 8; ++i)
#pragma unroll
        for (int j = 0; j < 8; ++j) acc[i][j] = 0.0f;

    for (int kk = 0; kk < Idim; kk += 16) {
        float4 av0 = *(const float4*)(xrow0 + kk + ak0);
        float4 av1 = *(const float4*)(xrow1 + kk + ak1);
        float4 bv0 = *(const float4*)(wrow0 + kk + ak0);
        float4 bv1 = *(const float4*)(wrow1 + kk + ak1);
        __syncthreads();
        As[ak0 + 0][ar0] = av0.x; As[ak0 + 1][ar0] = av0.y;
        As[ak0 + 2][ar0] = av0.z; As[ak0 + 3][ar0] = av0.w;
        As[ak1 + 0][ar1] = av1.x; As[ak1 + 1][ar1] = av1.y;
        As[ak1 + 2][ar1] = av1.z; As[ak1 + 3][ar1] = av1.w;
        Bs[ak0 + 0][ar0] = bv0.x; Bs[ak0 + 1][ar0] = bv0.y;
        Bs[ak0 + 2][ar0] = bv0.z; Bs[ak0 + 3][ar0] = bv0.w;
        Bs[ak1 + 0][ar1] = bv1.x; Bs[ak1 + 1][ar1] = bv1.y;
        Bs[ak1 + 2][ar1] = bv1.z; Bs[ak1 + 3][ar1] = bv1.w;
        __syncthreads();
#pragma unroll
        for (int k = 0; k < 16; ++k) {
            float4 a0 = *(const float4*)&As[k][tx * 4];
            float4 a1 = *(const float4*)&As[k][64 + tx * 4];
            float4 bq0 = *(const float4*)&Bs[k][ty * 4];
            float4 bq1 = *(const float4*)&Bs[k][64 + ty * 4];
            float a[8] = {a0.x, a0.y, a0.z, a0.w, a1.x, a1.y, a1.z, a1.w};
            float bb[8] = {bq0.x, bq0.y, bq0.z, bq0.w, bq1.x, bq1.y, bq1.z, bq1.w};
#pragma unroll
            for (int i = 0; i < 8; ++i)
#pragma unroll
                for (int j = 0; j < 8; ++j) acc[i][j] += a[i] * bb[j];
        }
    }

    const int n0 = bn * 128;
    float biasv[8];
#pragma unroll
    for (int j = 0; j < 8; ++j) {
        int c = (j < 4) ? (ty * 4 + j) : (64 + ty * 4 + (j - 4));
        biasv[j] = bi[n0 + c] + bh[n0 + c];
    }
#pragma unroll
    for (int i = 0; i < 8; ++i) {
        int r = (i < 4) ? (tx * 4 + i) : (64 + tx * 4 + (i - 4));
        size_t mrow = (size_t)(bm * 128 + r);
        float4 o0 = {acc[i][0] + biasv[0], acc[i][1] + biasv[1],
                     acc[i][2] + biasv[2], acc[i][3] + biasv[3]};
        float4 o1 = {acc[i][4] + biasv[4], acc[i][5] + biasv[5],
                     acc[i][6] + biasv[6], acc[i][7] + biasv[7]};
        *(float4*)(xp + mrow * Hdim + n0 + ty * 4) = o0;
        *(float4*)(xp + mrow * Hdim + n0 + 64 + ty * 4) = o1;
    }
}

// ---------------------------------------------------------------------------
// flags init (ws is re-poisoned to 0xAA before every timed launch)
// ---------------------------------------------------------------------------
__global__ void init_flags(int* flags) {
    if (threadIdx.x < NG) flags[threadIdx.x] = 0;
}

// ---------------------------------------------------------------------------
// Kernel B: register-resident-Wh scan.
// 128 WGs = 16 groups x 8 col-slices. WG (g,n): batches g*4..g*4+3,
// cols n*64..n*64+63. Wh slice (64x512 = 128KB) lives in VGPRs for the
// whole scan: thread (ct,kg) holds Wh[cols {ct, ct+32}][k in kg*32..+31]
// = 16 float4. Per step: partial FMAs from LDS-broadcast h, LDS reduction
// over 16 k-groups, tanh, write slice to hglob, 8-WG counter barrier,
// reload full h[4][512] from L2.
// Block swizzle: all 8 WGs of a group share wg%8 -> same XCD L2.
// ---------------------------------------------------------------------------
__global__ __launch_bounds__(512) void scan_reg(
        const float* __restrict__ xp, const float* __restrict__ Wh,
        float* __restrict__ hglob, int* __restrict__ flags, int t0, int CT) {
    const int wg = blockIdx.x;                       // 0..127
    // decode swizzle: wg = 64*(g>>3) + 8*n + (g&7)
    const int g = (wg & 7) + ((wg >> 6) << 3);       // 0..15
    const int n = (wg >> 3) & 7;                     // 0..7
    const int colbase = n * 64;
    const int bbase = g * PB;
    const int tid = threadIdx.x;
    const int ct = tid & 31;                         // col-thread 0..31
    const int kg = tid >> 5;                         // k-group 0..15 (32 k's)

    // --- load Wh fragment into registers (once) ---
    const float4* wsrcA = (const float4*)(Wh + (size_t)(colbase + ct) * Hdim + kg * 32);
    const float4* wsrcB = (const float4*)(Wh + (size_t)(colbase + 32 + ct) * Hdim + kg * 32);
    float4 wA[8], wB[8];
#pragma unroll
    for (int i = 0; i < 8; ++i) { wA[i] = wsrcA[i]; wB[i] = wsrcB[i]; }

    __shared__ float hs[PB][Hdim];                   // 8 KB
    __shared__ float red[16][PB][64];                // 16 KB

    // --- init h ---
    {
        const int b = tid >> 7, q = tid & 127;
        float4 v = {0.f, 0.f, 0.f, 0.f};
        if (t0 != 0)
            v = *(const float4*)(hglob + (size_t)(bbase + b) * Hdim + q * 4);
        *(float4*)&hs[b][q * 4] = v;
    }
    __syncthreads();

    const int fb = tid >> 6;                         // finalize batch (tid<256)
    const int fc = tid & 63;                         // finalize col-in-slice

    for (int t = 0; t < CT; ++t) {
        const int st = t0 + t;

        // prefetch xp for finalize (hides HBM/L3 latency under FMA block)
        float xv = 0.f;
        if (tid < 256)
            xv = xp[((size_t)(bbase + fb) * CT + t) * Hdim + colbase + fc];

        // --- partial GEMV on register Wh, broadcast h from LDS ---
        float p0[PB], p1[PB];
#pragma unroll
        for (int b = 0; b < PB; ++b) { p0[b] = 0.f; p1[b] = 0.f; }
#pragma unroll
        for (int i = 0; i < 8; ++i) {
#pragma unroll
            for (int b = 0; b < PB; ++b) {
                float4 hv = *(const float4*)&hs[b][kg * 32 + i * 4];
                p0[b] += wA[i].x * hv.x + wA[i].y * hv.y + wA[i].z * hv.z + wA[i].w * hv.w;
                p1[b] += wB[i].x * hv.x + wB[i].y * hv.y + wB[i].z * hv.z + wB[i].w * hv.w;
            }
        }
#pragma unroll
        for (int b = 0; b < PB; ++b) {
            red[kg][b][ct] = p0[b];
            red[kg][b][32 + ct] = p1[b];
        }
        __syncthreads();                             // (A) partials visible

        // --- finalize: reduce 16 k-groups, +xp, tanh, store slice ---
        if (tid < 256) {
            float s = 0.f;
#pragma unroll
            for (int k = 0; k < 16; ++k) s += red[k][fb][fc];
            s += xv;
            hglob[(size_t)(bbase + fb) * Hdim + colbase + fc] = tanhf(s);
        }
        __syncthreads();                             // (B) all stores drained

        // --- 8-WG monotone counter barrier (agent scope) ---
        if (tid == 0) {
            __hip_atomic_fetch_add(&flags[g], 1, __ATOMIC_RELEASE,
                                   __HIP_MEMORY_SCOPE_AGENT);
            while (__hip_atomic_load(&flags[g], __ATOMIC_ACQUIRE,
                                     __HIP_MEMORY_SCOPE_AGENT) < NSL * (st + 1)) {}
        }
        __syncthreads();                             // (C)

        // --- reload full h for our batches ---
        {
            const int b = tid >> 7, q = tid & 127;
            *(float4*)&hs[b][q * 4] =
                *(const float4*)(hglob + (size_t)(bbase + b) * Hdim + q * 4);
        }
        __syncthreads();                             // (D)
    }
}

// ---------------------------------------------------------------------------
// Kernel C: out[b][o] = dot(h_final[b,:], Wo[o,:]) + bo[o]
// ---------------------------------------------------------------------------
__global__ __launch_bounds__(256) void out_kernel(
        const float* __restrict__ hbuf, const float* __restrict__ Wo,
        const float* __restrict__ bo, float* __restrict__ out) {
    __shared__ float hsh[Hdim];
    const int b = blockIdx.x, o = threadIdx.x;
    hsh[o] = hbuf[b * Hdim + o];
    hsh[o + 256] = hbuf[b * Hdim + o + 256];
    __syncthreads();
    const float4* wrow = (const float4*)(Wo + (size_t)o * Hdim);
    const float4* h4 = (const float4*)hsh;
    float4 a4 = {0.0f, 0.0f, 0.0f, 0.0f};
#pragma unroll 4
    for (int i = 0; i < Hdim / 4; ++i) {
        float4 w = wrow[i];
        float4 hv = h4[i];
        a4.x += w.x * hv.x;
        a4.y += w.y * hv.y;
        a4.z += w.z * hv.z;
        a4.w += w.w * hv.w;
    }
    out[b * Odim + o] = bo[o] + ((a4.x + a4.y) + (a4.z + a4.w));
}

// ---------------------------------------------------------------------------
extern "C" void kernel_launch(void* const* d_in, const int* in_sizes, int n_in,
                              void* d_out, int out_size, void* d_ws, size_t ws_size,
                              hipStream_t stream) {
    const float* x  = (const float*)d_in[0];
    const float* Wi = (const float*)d_in[1];
    const float* bi = (const float*)d_in[2];
    const float* Wh = (const float*)d_in[3];
    const float* bh = (const float*)d_in[4];
    const float* Wo = (const float*)d_in[5];
    const float* bo = (const float*)d_in[6];
    float* out = (float*)d_out;

    const size_t hbytes = (size_t)Bsz * Hdim * sizeof(float);
    const size_t extrabytes = hbytes + 4096;  // hglob + flags
    int CT = Tlen;
    while (CT > 2 && (size_t)Bsz * CT * Hdim * sizeof(float) + extrabytes > ws_size)
        CT >>= 1;

    float* xp    = (float*)d_ws;
    float* hglob = (float*)((char*)d_ws + (size_t)Bsz * CT * Hdim * sizeof(float));
    int*   flags = (int*)((char*)hglob + hbytes);

    init_flags<<<1, 64, 0, stream>>>(flags);
    for (int t0 = 0; t0 < Tlen; t0 += CT) {
        xproj_kernel<<<dim3((Bsz * CT) / 128, Hdim / 128), 256, 0, stream>>>(
            x, Wi, bi, bh, xp, t0, CT);
        scan_reg<<<dim3(NG * NSL), 512, 0, stream>>>(xp, Wh, hglob, flags, t0, CT);
    }
    out_kernel<<<dim3(Bsz), 256, 0, stream>>>(hglob, Wo, bo, out);
}

// Round 3
// 2449.567 us; speedup vs baseline: 11.8636x; 2.2690x over previous
//
#include <hip/hip_runtime.h>
#include <math.h>

#define Bsz 64
#define Tlen 1024
#define Idim 256
#define Hdim 512
#define Odim 256

#define PB  2              // batches per sync-group
#define NSL 8              // column slices = WGs per group (64 cols each)
#define NG  (Bsz / PB)     // 32 groups -> 256 WGs total
#define FLAG_STRIDE 64     // ints; 256B between group flags (no shared lines)

// ---------------------------------------------------------------------------
// Kernel A: xproj[b][t][h] = dot(x[b, t0+t, :], Wi[h, :]) + bi[h] + bh[h]
// ---------------------------------------------------------------------------
__global__ __launch_bounds__(256) void xproj_kernel(
        const float* __restrict__ x, const float* __restrict__ Wi,
        const float* __restrict__ bi, const float* __restrict__ bh,
        float* __restrict__ xp, int t0, int CT) {
    __shared__ float As[16][132];
    __shared__ float Bs[16][132];
    const int tid = threadIdx.x;
    const int bm = blockIdx.x, bn = blockIdx.y;
    const int tx = tid & 15, ty = tid >> 4;

    const int f0 = tid, f1 = tid + 256;
    const int ar0 = f0 >> 2, ak0 = (f0 & 3) * 4;
    const int ar1 = f1 >> 2, ak1 = (f1 & 3) * 4;
    const int m0g = bm * 128 + ar0;
    const int m1g = bm * 128 + ar1;
    const int b0 = m0g / CT, tt0 = m0g - b0 * CT;
    const int b1 = m1g / CT, tt1 = m1g - b1 * CT;
    const float* xrow0 = x + ((size_t)b0 * Tlen + t0 + tt0) * Idim;
    const float* xrow1 = x + ((size_t)b1 * Tlen + t0 + tt1) * Idim;
    const float* wrow0 = Wi + (size_t)(bn * 128 + ar0) * Idim;
    const float* wrow1 = Wi + (size_t)(bn * 128 + ar1) * Idim;

    float acc[8][8];
#pragma unroll
    for (int i = 0; i < 8; ++i)
#pragma unroll
        for (int j = 0; j < 8; ++j) acc[i][j] = 0.0f;

    for (int kk = 0; kk < Idim; kk += 16) {
        float4 av0 = *(const float4*)(xrow0 + kk + ak0);
        float4 av1 = *(const float4*)(xrow1 + kk + ak1);
        float4 bv0 = *(const float4*)(wrow0 + kk + ak0);
        float4 bv1 = *(const float4*)(wrow1 + kk + ak1);
        __syncthreads();
        As[ak0 + 0][ar0] = av0.x; As[ak0 + 1][ar0] = av0.y;
        As[ak0 + 2][ar0] = av0.z; As[ak0 + 3][ar0] = av0.w;
        As[ak1 + 0][ar1] = av1.x; As[ak1 + 1][ar1] = av1.y;
        As[ak1 + 2][ar1] = av1.z; As[ak1 + 3][ar1] = av1.w;
        Bs[ak0 + 0][ar0] = bv0.x; Bs[ak0 + 1][ar0] = bv0.y;
        Bs[ak0 + 2][ar0] = bv0.z; Bs[ak0 + 3][ar0] = bv0.w;
        Bs[ak1 + 0][ar1] = bv1.x; Bs[ak1 + 1][ar1] = bv1.y;
        Bs[ak1 + 2][ar1] = bv1.z; Bs[ak1 + 3][ar1] = bv1.w;
        __syncthreads();
#pragma unroll
        for (int k = 0; k < 16; ++k) {
            float4 a0 = *(const float4*)&As[k][tx * 4];
            float4 a1 = *(const float4*)&As[k][64 + tx * 4];
            float4 bq0 = *(const float4*)&Bs[k][ty * 4];
            float4 bq1 = *(const float4*)&Bs[k][64 + ty * 4];
            float a[8] = {a0.x, a0.y, a0.z, a0.w, a1.x, a1.y, a1.z, a1.w};
            float bb[8] = {bq0.x, bq0.y, bq0.z, bq0.w, bq1.x, bq1.y, bq1.z, bq1.w};
#pragma unroll
            for (int i = 0; i < 8; ++i)
#pragma unroll
                for (int j = 0; j < 8; ++j) acc[i][j] += a[i] * bb[j];
        }
    }

    const int n0 = bn * 128;
    float biasv[8];
#pragma unroll
    for (int j = 0; j < 8; ++j) {
        int c = (j < 4) ? (ty * 4 + j) : (64 + ty * 4 + (j - 4));
        biasv[j] = bi[n0 + c] + bh[n0 + c];
    }
#pragma unroll
    for (int i = 0; i < 8; ++i) {
        int r = (i < 4) ? (tx * 4 + i) : (64 + tx * 4 + (i - 4));
        size_t mrow = (size_t)(bm * 128 + r);
        float4 o0 = {acc[i][0] + biasv[0], acc[i][1] + biasv[1],
                     acc[i][2] + biasv[2], acc[i][3] + biasv[3]};
        float4 o1 = {acc[i][4] + biasv[4], acc[i][5] + biasv[5],
                     acc[i][6] + biasv[6], acc[i][7] + biasv[7]};
        *(float4*)(xp + mrow * Hdim + n0 + ty * 4) = o0;
        *(float4*)(xp + mrow * Hdim + n0 + 64 + ty * 4) = o1;
    }
}

// ---------------------------------------------------------------------------
__global__ void init_flags(int* flags) {
    int i = blockIdx.x * blockDim.x + threadIdx.x;
    if (i < NG * FLAG_STRIDE) flags[i] = 0;
}

// ---------------------------------------------------------------------------
// Kernel B: register-resident-Wh scan, relaxed write-through exchange.
// 256 WGs = 32 groups x 8 col-slices; WG (g,n): batches g*2..g*2+1,
// cols n*64..n*64+63. Thread (ct=tid&15, kg=tid>>4) owns cols ct*4..+3
// of the slice, k's kg*16..+15 -> 16 float4 of Wh in VGPRs.
// Per step: FMA partials from LDS-broadcast h -> float4 partial per batch
// -> LDS reduce over 32 k-groups -> tanh -> write-through store to
// double-buffered hglob[(st+1)&1] -> padded relaxed counter barrier ->
// read-through reload of the 7 foreign slices.
// Swizzle: all 8 WGs of a group share wg%8 (same XCD L2 round-robin).
// ---------------------------------------------------------------------------
__global__ __launch_bounds__(512) void scan_reg(
        const float* __restrict__ xp, const float* __restrict__ Wh,
        float* __restrict__ hglob, int* __restrict__ flags, int t0, int CT) {
    const int wg = blockIdx.x;                        // 0..255
    const int g = (wg & 7) + ((wg >> 6) << 3);        // 0..31
    const int n = (wg >> 3) & 7;                      // 0..7
    const int colbase = n * 64;
    const int bbase = g * PB;
    const int tid = threadIdx.x;
    const int ct = tid & 15;                          // col-group 0..15
    const int kg = tid >> 4;                          // k-group 0..31

    // --- Wh fragment into registers (once): w[cc][i] ---
    float4 w[4][4];
#pragma unroll
    for (int cc = 0; cc < 4; ++cc) {
        const float4* src =
            (const float4*)(Wh + (size_t)(colbase + ct * 4 + cc) * Hdim + kg * 16);
#pragma unroll
        for (int i = 0; i < 4; ++i) w[cc][i] = src[i];
    }

    __shared__ float  hs[PB][Hdim];                   // 4 KB
    __shared__ float4 red4[PB][32][17];               // ~17.4 KB, padded

    // --- init h (read-through; buffer t0&1 holds h_{t0}) ---
    if (tid < 256) {
        const int b = tid >> 7, q = tid & 127;
        const size_t base = ((size_t)(t0 & 1) * Bsz + bbase + b) * Hdim + q * 4;
#pragma unroll
        for (int j = 0; j < 4; ++j) {
            float v = 0.f;
            if (t0 != 0)
                v = __hip_atomic_load(&hglob[base + j], __ATOMIC_RELAXED,
                                      __HIP_MEMORY_SCOPE_AGENT);
            hs[b][q * 4 + j] = v;
        }
    }
    __syncthreads();

    const int fb = tid >> 6;                          // finalize batch (tid<128)
    const int fc = tid & 63;                          // finalize col-in-slice
    int* const flag = &flags[g * FLAG_STRIDE];

    // prefetch xp for t=0
    float xv = 0.f;
    if (tid < 128)
        xv = xp[((size_t)(bbase + fb) * CT) * Hdim + colbase + fc];

    for (int t = 0; t < CT; ++t) {
        const int st = t0 + t;
        const int nb = (st + 1) & 1;                  // buffer for h_{st+1}

        // --- partial GEMV: register Wh x LDS-broadcast h ---
        float4 p0 = {0.f, 0.f, 0.f, 0.f};
        float4 p1 = {0.f, 0.f, 0.f, 0.f};
#pragma unroll
        for (int i = 0; i < 4; ++i) {
            float4 h0 = *(const float4*)&hs[0][kg * 16 + i * 4];
            float4 h1 = *(const float4*)&hs[1][kg * 16 + i * 4];
            p0.x += w[0][i].x * h0.x + w[0][i].y * h0.y + w[0][i].z * h0.z + w[0][i].w * h0.w;
            p0.y += w[1][i].x * h0.x + w[1][i].y * h0.y + w[1][i].z * h0.z + w[1][i].w * h0.w;
            p0.z += w[2][i].x * h0.x + w[2][i].y * h0.y + w[2][i].z * h0.z + w[2][i].w * h0.w;
            p0.w += w[3][i].x * h0.x + w[3][i].y * h0.y + w[3][i].z * h0.z + w[3][i].w * h0.w;
            p1.x += w[0][i].x * h1.x + w[0][i].y * h1.y + w[0][i].z * h1.z + w[0][i].w * h1.w;
            p1.y += w[1][i].x * h1.x + w[1][i].y * h1.y + w[1][i].z * h1.z + w[1][i].w * h1.w;
            p1.z += w[2][i].x * h1.x + w[2][i].y * h1.y + w[2][i].z * h1.z + w[2][i].w * h1.w;
            p1.w += w[3][i].x * h1.x + w[3][i].y * h1.y + w[3][i].z * h1.z + w[3][i].w * h1.w;
        }
        red4[0][kg][ct] = p0;
        red4[1][kg][ct] = p1;
        __syncthreads();                              // (A) partials visible

        // --- finalize: reduce 32 k-groups, +xp, tanh, write-through store ---
        if (tid < 128) {
            float s = 0.f;
#pragma unroll
            for (int k = 0; k < 32; ++k)
                s += ((const float*)&red4[fb][k][0])[fc];
            float h1v = tanhf(s + xv);
            __hip_atomic_store(
                &hglob[((size_t)nb * Bsz + bbase + fb) * Hdim + colbase + fc],
                h1v, __ATOMIC_RELAXED, __HIP_MEMORY_SCOPE_AGENT);
            hs[fb][colbase + fc] = h1v;               // own slice via LDS
        }
        __syncthreads();                              // (B) all stores drained

        // --- padded relaxed counter barrier ---
        if (tid == 0)
            __hip_atomic_fetch_add(flag, 1, __ATOMIC_RELAXED,
                                   __HIP_MEMORY_SCOPE_AGENT);

        // prefetch next xp while we wait
        if (tid < 128 && t + 1 < CT)
            xv = xp[((size_t)(bbase + fb) * CT + (t + 1)) * Hdim + colbase + fc];

        if (tid == 0) {
            while (__hip_atomic_load(flag, __ATOMIC_RELAXED,
                                     __HIP_MEMORY_SCOPE_AGENT) < NSL * (st + 1)) {}
        }
        __syncthreads();                              // (C) barrier passed

        // --- read-through reload of the 7 foreign slices ---
        if (tid < 256) {
            const int b = tid >> 7, q = tid & 127;
            if ((q >> 4) != n) {
                const size_t base =
                    ((size_t)nb * Bsz + bbase + b) * Hdim + q * 4;
#pragma unroll
                for (int j = 0; j < 4; ++j)
                    hs[b][q * 4 + j] =
                        __hip_atomic_load(&hglob[base + j], __ATOMIC_RELAXED,
                                          __HIP_MEMORY_SCOPE_AGENT);
            }
        }
        __syncthreads();                              // (D) h_{st+1} ready
    }
}

// ---------------------------------------------------------------------------
// Kernel C: out[b][o] = dot(h_final[b,:], Wo[o,:]) + bo[o]
// h_final lives in hglob buffer (Tlen&1)==0 -> base pointer.
// ---------------------------------------------------------------------------
__global__ __launch_bounds__(256) void out_kernel(
        const float* __restrict__ hbuf, const float* __restrict__ Wo,
        const float* __restrict__ bo, float* __restrict__ out) {
    __shared__ float hsh[Hdim];
    const int b = blockIdx.x, o = threadIdx.x;
    hsh[o] = hbuf[b * Hdim + o];
    hsh[o + 256] = hbuf[b * Hdim + o + 256];
    __syncthreads();
    const float4* wrow = (const float4*)(Wo + (size_t)o * Hdim);
    const float4* h4 = (const float4*)hsh;
    float4 a4 = {0.0f, 0.0f, 0.0f, 0.0f};
#pragma unroll 4
    for (int i = 0; i < Hdim / 4; ++i) {
        float4 ww = wrow[i];
        float4 hv = h4[i];
        a4.x += ww.x * hv.x;
        a4.y += ww.y * hv.y;
        a4.z += ww.z * hv.z;
        a4.w += ww.w * hv.w;
    }
    out[b * Odim + o] = bo[o] + ((a4.x + a4.y) + (a4.z + a4.w));
}

// ---------------------------------------------------------------------------
extern "C" void kernel_launch(void* const* d_in, const int* in_sizes, int n_in,
                              void* d_out, int out_size, void* d_ws, size_t ws_size,
                              hipStream_t stream) {
    const float* x  = (const float*)d_in[0];
    const float* Wi = (const float*)d_in[1];
    const float* bi = (const float*)d_in[2];
    const float* Wh = (const float*)d_in[3];
    const float* bh = (const float*)d_in[4];
    const float* Wo = (const float*)d_in[5];
    const float* bo = (const float*)d_in[6];
    float* out = (float*)d_out;

    const size_t hbytes = 2ull * Bsz * Hdim * sizeof(float);   // double buffer
    const size_t fbytes = (size_t)NG * FLAG_STRIDE * sizeof(int);
    const size_t extrabytes = hbytes + fbytes;
    int CT = Tlen;
    while (CT > 2 && (size_t)Bsz * CT * Hdim * sizeof(float) + extrabytes > ws_size)
        CT >>= 1;

    float* xp    = (float*)d_ws;
    float* hglob = (float*)((char*)d_ws + (size_t)Bsz * CT * Hdim * sizeof(float));
    int*   flags = (int*)((char*)hglob + hbytes);

    init_flags<<<dim3((NG * FLAG_STRIDE + 255) / 256), 256, 0, stream>>>(flags);
    for (int t0 = 0; t0 < Tlen; t0 += CT) {
        xproj_kernel<<<dim3((Bsz * CT) / 128, Hdim / 128), 256, 0, stream>>>(
            x, Wi, bi, bh, xp, t0, CT);
        scan_reg<<<dim3(NG * NSL), 512, 0, stream>>>(xp, Wh, hglob, flags, t0, CT);
    }
    // h_final is in buffer (Tlen & 1) == 0 -> hglob base
    out_kernel<<<dim3(Bsz), 256, 0, stream>>>(hglob, Wo, bo, out);
}